// Round 13
// baseline (739.607 us; speedup 1.0000x reference)
//
#include <hip/hip_runtime.h>

namespace {

constexpr int Tn = 1000, Fn = 22, Hn = 10, Cn = 4;

typedef __fp16 f16x2 __attribute__((ext_vector_type(2)));
typedef __fp16 f16x4 __attribute__((ext_vector_type(4)));
typedef __fp16 f16x8 __attribute__((ext_vector_type(8)));
typedef float  f32x2 __attribute__((ext_vector_type(2)));
typedef float  f32x4 __attribute__((ext_vector_type(4)));
typedef unsigned u32;
typedef u32 u32x2 __attribute__((ext_vector_type(2)));
typedef u32 u32x4 __attribute__((ext_vector_type(4)));

__device__ __forceinline__ f16x4 pack4(float a, float b, float c, float d) {
    f16x2 lo = __builtin_amdgcn_cvt_pkrtz(a, b);
    f16x2 hi = __builtin_amdgcn_cvt_pkrtz(c, d);
    u32x2 u; u.x = __builtin_bit_cast(u32, lo); u.y = __builtin_bit_cast(u32, hi);
    return __builtin_bit_cast(f16x4, u);
}
__device__ __forceinline__ f16x4 packrelu(f32x4 v) {
    return pack4(fmaxf(v.x, 0.f), fmaxf(v.y, 0.f), fmaxf(v.z, 0.f), fmaxf(v.w, 0.f));
}

__global__ __launch_bounds__(64, 1) void rnn_mfma(
    const float* __restrict__ x,
    const float* __restrict__ w_ih0, const float* __restrict__ w_hh0,
    const float* __restrict__ b_ih0, const float* __restrict__ b_hh0,
    const float* __restrict__ w_ih1, const float* __restrict__ w_hh1,
    const float* __restrict__ b_ih1, const float* __restrict__ b_hh1,
    const float* __restrict__ w_lin, const float* __restrict__ b_lin,
    float* __restrict__ out)
{
    const int lane = threadIdx.x;       // one wave per block, 16 batches per wave
    const int c16  = lane & 15;         // weight row (A) / batch column (B, C/D)
    const int q    = lane >> 4;         // K-quarter
    const int bg   = blockIdx.x * 16;   // first batch of this wave

    // ---- A fragments (A[i][k]: i = lane&15, k = 4q+e; K16) ----
    auto ldA16 = [&](const float* w, int rows) -> f16x4 {
        float v[4];
        #pragma unroll
        for (int e = 0; e < 4; ++e) {
            const int k = 4*q + e;
            v[e] = (c16 < rows && k < Hn) ? w[c16*Hn + k] : 0.f;
        }
        return pack4(v[0], v[1], v[2], v[3]);
    };
    const f16x4 Ahh0 = ldA16(w_hh0, Hn);
    const f16x4 Aih1 = ldA16(w_ih1, Hn);
    const f16x4 Ahh1 = ldA16(w_hh1, Hn);
    const f16x4 Alin = ldA16(w_lin, Cn);

    // A for z-MFMA (K32: k = 8q+e, e=0..7); cols >= Fn zero -> X pad garbage killed
    f16x8 Aih0;
    {
        float v[8];
        #pragma unroll
        for (int e = 0; e < 8; ++e) {
            const int k = 8*q + e;
            v[e] = (c16 < Hn && k < Fn) ? w_ih0[c16*Fn + k] : 0.f;
        }
        f16x2 p0 = __builtin_amdgcn_cvt_pkrtz(v[0], v[1]);
        f16x2 p1 = __builtin_amdgcn_cvt_pkrtz(v[2], v[3]);
        f16x2 p2 = __builtin_amdgcn_cvt_pkrtz(v[4], v[5]);
        f16x2 p3 = __builtin_amdgcn_cvt_pkrtz(v[6], v[7]);
        u32x4 u; u.x = __builtin_bit_cast(u32, p0); u.y = __builtin_bit_cast(u32, p1);
                 u.z = __builtin_bit_cast(u32, p2); u.w = __builtin_bit_cast(u32, p3);
        Aih0 = __builtin_bit_cast(f16x8, u);
    }

    // ---- C fragments (C[r][c]: row = 4q+r, same value across cols) ----
    f32x4 Cb1, Cb2, Cbl;
    #pragma unroll
    for (int r = 0; r < 4; ++r) {
        const int rr = 4*q + r;
        Cb1[r] = (rr < Hn) ? (b_ih0[rr] + b_hh0[rr]) : 0.f;
        Cb2[r] = (rr < Hn) ? (b_ih1[rr] + b_hh1[rr]) : 0.f;
        Cbl[r] = (rr < Cn) ? b_lin[rr] : 0.f;
    }

    // ---- x register ring: 8 slots; lane holds features 8q..8q+7 of its batch.
    // f32x2 loads only (p is always 8B-aligned; t*88B breaks 16B alignment).
    // q==2: features 16-21 valid (3 pairs); q==3: all zero.
    const float* __restrict__ xlane = x + (size_t)(bg + c16) * (Tn * Fn) + 8*q;
    f32x2 r0[8], r1[8], r2[8], r3[8];
    #pragma unroll
    for (int s = 0; s < 8; ++s) {
        r0[s] = f32x2{0,0}; r1[s] = f32x2{0,0};
        r2[s] = f32x2{0,0}; r3[s] = f32x2{0,0};
    }

    auto refill = [&](int s, int t) {            // s static, t runtime
        const float* p = xlane + t * Fn;
        if (q < 2) {
            r0[s] = *(const f32x2*)p;
            r1[s] = *(const f32x2*)(p + 2);
            r2[s] = *(const f32x2*)(p + 4);
            r3[s] = *(const f32x2*)(p + 6);
        } else if (q == 2) {
            r0[s] = *(const f32x2*)p;
            r1[s] = *(const f32x2*)(p + 2);
            r2[s] = *(const f32x2*)(p + 4);      // r3 stays 0
        }
    };
    auto cvtx = [&](int s) -> f16x8 {            // f32 ring slot -> B fragment
        f16x2 p0 = __builtin_amdgcn_cvt_pkrtz(r0[s].x, r0[s].y);
        f16x2 p1 = __builtin_amdgcn_cvt_pkrtz(r1[s].x, r1[s].y);
        f16x2 p2 = __builtin_amdgcn_cvt_pkrtz(r2[s].x, r2[s].y);
        f16x2 p3 = __builtin_amdgcn_cvt_pkrtz(r3[s].x, r3[s].y);
        u32x4 u; u.x = __builtin_bit_cast(u32, p0); u.y = __builtin_bit_cast(u32, p1);
                 u.z = __builtin_bit_cast(u32, p2); u.w = __builtin_bit_cast(u32, p3);
        return __builtin_bit_cast(f16x8, u);
    };

    // ---- prologue: fill ring with X(0..7); Z(0); re-arm slot 0 with X(8) ----
    #pragma unroll
    for (int s = 0; s < 8; ++s) refill(s, s);

    f16x4 H1 = __builtin_bit_cast(f16x4, u32x2{0,0});   // h1(-1) = 0
    f16x4 H2 = __builtin_bit_cast(f16x4, u32x2{0,0});   // h2(-1) = 0

    f16x8 x0 = cvtx(0);                                  // waits slot-0 loads
    f32x4 Zcur = __builtin_amdgcn_mfma_f32_16x16x32_f16(Aih0, x0, Cb1, 0, 0, 0);
    refill(0, 8);

    // ---- main loop: t = 8*it + s ----
    #pragma unroll 1
    for (int it = 0; it < 125; ++it) {
        const int tb = it * 8;
        #pragma unroll
        for (int s = 0; s < 8; ++s) {
            const int sn = (s + 1) & 7;
            // X(t+1) -> B fragment (off-chain; vmcnt wait lands here)
            f16x8 xn = cvtx(sn);
            // L2 recurrent part with OLD H2 (independent of this step's chain)
            f32x4 m2a = __builtin_amdgcn_mfma_f32_16x16x16f16(Ahh1, H2, Cb2, 0, 0, 0);
            // Z(t+1) (consumed next step)
            f32x4 zn = __builtin_amdgcn_mfma_f32_16x16x32_f16(Aih0, xn, Cb1, 0, 0, 0);
            // chain: D1 = W_hh0*H1(t-1) + Z(t)
            f32x4 d1 = __builtin_amdgcn_mfma_f32_16x16x16f16(Ahh0, H1, Zcur, 0, 0, 0);
            // re-arm ring slot with X(t+9) while D1 is in the pipe
            { int t9 = tb + s + 9; if (t9 > 999) t9 = 999; refill(sn, t9); }
            // H1(t) = relu(D1)  [D layout == B layout: in-lane pack]
            H1 = packrelu(d1);
            // D2 = W_ih1*H1(t) + m2a ; H2(t) = relu(D2)
            f32x4 d2 = __builtin_amdgcn_mfma_f32_16x16x16f16(Aih1, H1, m2a, 0, 0, 0);
            H2 = packrelu(d2);
            Zcur = zn;
        }
    }

    // ---- head: D = W_lin*H2(999) + b_lin ; lanes 0-15 hold classes 0-3 ----
    f32x4 dh = __builtin_amdgcn_mfma_f32_16x16x16f16(Alin, H2, Cbl, 0, 0, 0);
    if (lane < 16)
        *(f32x4*)(out + (size_t)(bg + lane) * Cn) = dh;
}

} // namespace

extern "C" void kernel_launch(void* const* d_in, const int* in_sizes, int n_in,
                              void* d_out, int out_size, void* d_ws, size_t ws_size,
                              hipStream_t stream) {
    const float* x     = (const float*)d_in[0];
    const float* w_ih0 = (const float*)d_in[1];
    const float* w_hh0 = (const float*)d_in[2];
    const float* b_ih0 = (const float*)d_in[3];
    const float* b_hh0 = (const float*)d_in[4];
    const float* w_ih1 = (const float*)d_in[5];
    const float* w_hh1 = (const float*)d_in[6];
    const float* b_ih1 = (const float*)d_in[7];
    const float* b_hh1 = (const float*)d_in[8];
    const float* w_lin = (const float*)d_in[9];
    const float* b_lin = (const float*)d_in[10];
    float* out = (float*)d_out;

    // 16 batches per wave via MFMA; 1024/16 = 64 blocks of one wave each
    rnn_mfma<<<dim3(64), dim3(64), 0, stream>>>(
        x, w_ih0, w_hh0, b_ih0, b_hh0,
        w_ih1, w_hh1, b_ih1, b_hh1, w_lin, b_lin, out);
}